// Round 2
// 236.145 us; speedup vs baseline: 1.0189x; 1.0189x over previous
//
#include <hip/hip_runtime.h>
#include <stdint.h>

typedef __attribute__((ext_vector_type(8))) _Float16 half8;  // MFMA f16 A/B frag (4 VGPRs)
typedef __attribute__((ext_vector_type(4))) float f32x4;     // MFMA C/D frag

// B=4, C=384, Q=384, H=256, K=256
// ws: [0, 393216) Wsplit fp16 [3][256][256] = W_h, W_u, W_hu, layout [k][h]
// NOTE: w1 is (K=256 rows, 3H=768 cols): W_m[k][h] = w1[k][m*256 + h]  (axis-0 is k!)

__device__ __forceinline__ float leaky(float x) { return fmaxf(x, 0.01f * x); }

template <int CTRL>
__device__ __forceinline__ float dpp_add(float x) {
  int t = __builtin_amdgcn_update_dpp(0, __float_as_int(x), CTRL, 0xF, 0xF, true);
  return x + __int_as_float(t);
}

// 16-lane sum (within each aligned 16-lane group): xor1, xor2, then +ror4 +ror8
__device__ __forceinline__ float row16_sum(float p) {
  p = dpp_add<0xB1>(p);   // quad_perm(1,0,3,2)  = xor 1
  p = dpp_add<0x4E>(p);   // quad_perm(2,3,0,1)  = xor 2
  p = dpp_add<0x124>(p);  // row_ror:4
  p = dpp_add<0x128>(p);  // row_ror:8  -> full 16-lane sum in every lane
  return p;
}

// ---------------- K0: split w1 (256 k-rows, 768 h-cols) -> fp16 [3][k][h] -----------
__global__ void k_convert(const float* __restrict__ w1, unsigned int* __restrict__ ws) {
  int d = blockIdx.x * 256 + threadIdx.x;        // 98304 dwords (2 fp16 each, along h)
  int m = d >> 15;                               // matrix 0..2
  int rem = d & 32767;
  int k = rem >> 7;
  int h2 = (rem & 127) * 2;
  float x0 = w1[k * 768 + m * 256 + h2];         // w1[k][m*256+h] — axis-0 is k
  float x1 = w1[k * 768 + m * 256 + h2 + 1];
  unsigned short p0 = __builtin_bit_cast(unsigned short, (_Float16)x0);
  unsigned short p1 = __builtin_bit_cast(unsigned short, (_Float16)x1);
  ws[d] = (unsigned int)p0 | ((unsigned int)p1 << 16);
}

// ---------------- K1: fused main kernel ---------------------------------------------
// Block: 16 q-rows x 256 k x 24 c. 256 threads = 4 waves, wave w owns k in [w*64, w*64+64),
// lane (quad,r) holds k = w*64 + 4r + j (j = 0..3)
// Key restructure vs previous 240us version:
//   term_u[q,k]+b1 precomputed ONCE into registers (tuacc) -> wu regs eliminated (-128 VGPR)
//   per-c B operand is fixed (whu); A operand = u ⊙ h[c] computed on the fly (4x fewer pk-FMA)
//   q-tile 16 -> live set ~230 VGPR -> 2 waves/SIMD (was spilling at 1 wave/SIMD)
//   no barriers in the c-loop; one final cross-wave combine
__global__ void __launch_bounds__(256, 2) k_main(
    const float* __restrict__ hp, const float* __restrict__ up,
    const _Float16* __restrict__ wsp,
    const float* __restrict__ b1, const float* __restrict__ w2,
    const float* __restrict__ b2, float* __restrict__ out) {
  __shared__ __align__(16) float thlds[24 * 256];      // term_h (pure), fp32, 24 KB
  __shared__ __align__(16) _Float16 hlds[24 * 256];    // h rows, fp16, 12 KB
  __shared__ float redw[24][4][16];                    // per-c per-wave partials, 6 KB

  const int tid = threadIdx.x;
  const int blk = blockIdx.x;            // 1536 = 4 b * 24 qt * 16 cc
  const int b = blk / 384;
  const int r0 = blk % 384;
  const int qt = r0 % 24;
  const int cc = r0 / 24;
  const int q0 = qt * 16;
  const int c0 = cc * 24;

  const int w = tid >> 6, l = tid & 63, quad = l >> 4, r = l & 15;
  const int kbase = w * 64 + r * 4;      // lane's 4 k-columns = kbase + j

  const _Float16* Wh = wsp;
  const _Float16* Wu = wsp + 65536;
  const _Float16* Whu = wsp + 131072;

  // ---- stage h rows into LDS as packed fp16, layout [c][h] linear ----
  for (int d = tid; d < 24 * 128; d += 256) {          // 3072 dwords
    int c = d >> 7;
    int hidx = (d & 127) * 2;
    const float* hr = hp + (b * 384 + c0 + c) * 256 + hidx;
    unsigned short p0 = __builtin_bit_cast(unsigned short, (_Float16)hr[0]);
    unsigned short p1 = __builtin_bit_cast(unsigned short, (_Float16)hr[1]);
    ((unsigned int*)hlds)[d] = (unsigned int)p0 | ((unsigned int)p1 << 16);
  }

  // ---- one-time register frags: u rows (A operand) ----
  half8 ufr[8];                          // u[q0+r][s*32+quad*8 .. +8]
  {
    const float* urow = up + (b * 384 + q0 + r) * 256 + quad * 8;
#pragma unroll
    for (int s = 0; s < 8; ++s) {
      float4 a0 = *(const float4*)(urow + s * 32);
      float4 a1 = *(const float4*)(urow + s * 32 + 4);
      half8 hv;
      hv[0] = (_Float16)a0.x; hv[1] = (_Float16)a0.y;
      hv[2] = (_Float16)a0.z; hv[3] = (_Float16)a0.w;
      hv[4] = (_Float16)a1.x; hv[5] = (_Float16)a1.y;
      hv[6] = (_Float16)a1.z; hv[7] = (_Float16)a1.w;
      ufr[s] = hv;
    }
  }

  // ---- tu pass: tuacc[j][ii] = b1[kbase+j] + term_u[q0+quad*4+ii][kbase+j] ----
  // (c-independent; Wu frags are transient — freed before whu is loaded)
  f32x4 tuacc[4];
  {
    f32x4 b1v = *(const f32x4*)(b1 + kbase);
#pragma unroll
    for (int j = 0; j < 4; ++j) tuacc[j] = (f32x4){b1v[j], b1v[j], b1v[j], b1v[j]};
#pragma unroll
    for (int s = 0; s < 8; ++s) {
#pragma unroll
      for (int j = 0; j < 4; ++j) {
        half8 wuf = *(const half8*)(Wu + (kbase + j) * 256 + s * 32 + quad * 8);
        tuacc[j] = __builtin_amdgcn_mfma_f32_16x16x32_f16(ufr[s], wuf, tuacc[j], 0, 0, 0);
      }
    }
  }

  // ---- persistent B operands: W_hu rows for this wave's 64 k ----
  half8 whu[4][8];
#pragma unroll
  for (int j = 0; j < 4; ++j) {
    const _Float16* rowu = Whu + (kbase + j) * 256 + quad * 8;
#pragma unroll
    for (int s = 0; s < 8; ++s) whu[j][s] = *(const half8*)(rowu + s * 32);
  }

  __syncthreads();   // hlds ready

  // ---- prologue MFMA pass: term_h for the block's 24 c-rows -> thlds (pure, no b1) ----
#pragma unroll
  for (int ct = 0; ct < 2; ++ct) {
    f32x4 accq[4];
#pragma unroll
    for (int j = 0; j < 4; ++j) accq[j] = (f32x4){0.f, 0.f, 0.f, 0.f};
#pragma unroll
    for (int s = 0; s < 8; ++s) {
      half8 ha = (half8){};
      if (ct * 16 + r < 24) ha = *(const half8*)&hlds[(ct * 16 + r) * 256 + s * 32 + quad * 8];
#pragma unroll
      for (int j = 0; j < 4; ++j) {
        half8 wb = *(const half8*)(Wh + (kbase + j) * 256 + s * 32 + quad * 8);
        accq[j] = __builtin_amdgcn_mfma_f32_16x16x32_f16(ha, wb, accq[j], 0, 0, 0);
      }
    }
#pragma unroll
    for (int ii = 0; ii < 4; ++ii) {
      int crow = ct * 16 + quad * 4 + ii;
      if (crow < 24) {
        f32x4 v = {accq[0][ii], accq[1][ii], accq[2][ii], accq[3][ii]};
        *(f32x4*)&thlds[crow * 256 + kbase] = v;
      }
    }
  }
  __syncthreads();   // thlds ready

  // ---- main c-loop: barrier-free ----
  f32x4 w2v = *(const f32x4*)(w2 + kbase);
  f32x4 w2a = w2v * 0.505f;     // leaky(x)*w2 = w2*(0.505x + 0.495|x|)
  f32x4 w2b = w2v * 0.495f;

  for (int c = 0; c < 24; ++c) {
    f32x4 thv = *(const f32x4*)&thlds[c * 256 + kbase];
    f32x4 acc[4];
#pragma unroll
    for (int j = 0; j < 4; ++j) {
      float t = thv[j];
      acc[j] = tuacc[j] + (f32x4){t, t, t, t};
    }

#pragma unroll
    for (int s = 0; s < 8; ++s) {
      half8 hc = *(const half8*)&hlds[c * 256 + s * 32 + quad * 8];
      half8 au = ufr[s] * hc;                         // v_pk_mul_f16: A = u ⊙ h[c]
#pragma unroll
      for (int j = 0; j < 4; ++j)
        acc[j] = __builtin_amdgcn_mfma_f32_16x16x32_f16(au, whu[j][s], acc[j], 0, 0, 0);
    }

    // epilogue: layer-2 dot over this wave's 64 k, DPP-reduce over the 16 r-lanes
#pragma unroll
    for (int ii = 0; ii < 4; ++ii) {
      float p = 0.f;
#pragma unroll
      for (int j = 0; j < 4; ++j) {
        float sv = acc[j][ii];
        p = fmaf(w2a[j], sv, p);
        p = fmaf(w2b[j], fabsf(sv), p);
      }
      p = row16_sum(p);
      if (r == 0) redw[c][w][quad * 4 + ii] = p;
    }
  }

  __syncthreads();   // all partials in redw

  // ---- final cross-wave combine + bias + leaky + store ----
  const float b2v = b2[0];
  for (int idx = tid; idx < 24 * 16; idx += 256) {
    int c = idx >> 4;
    int q = idx & 15;
    float o = redw[c][0][q] + redw[c][1][q] + redw[c][2][q] + redw[c][3][q] + b2v;
    out[(b * 384 + c0 + c) * 384 + q0 + q] = leaky(o);
  }
}

extern "C" void kernel_launch(void* const* d_in, const int* in_sizes, int n_in,
                              void* d_out, int out_size, void* d_ws, size_t ws_size,
                              hipStream_t stream) {
  const float* hp = (const float*)d_in[0];   // (4,384,256)
  const float* up = (const float*)d_in[1];   // (4,384,256)
  const float* w1 = (const float*)d_in[2];   // (256,768) — axis-0 is k
  const float* b1 = (const float*)d_in[3];   // (256,)
  const float* w2 = (const float*)d_in[4];   // (1,256)
  const float* b2 = (const float*)d_in[5];   // (1,)
  float* out = (float*)d_out;                // (4,384,384)

  unsigned int* wsplit = (unsigned int*)d_ws;   // fp16 [3][256][256]

  k_convert<<<384, 256, 0, stream>>>(w1, wsplit);
  k_main<<<1536, 256, 0, stream>>>(hp, up, (const _Float16*)d_ws, b1, w2, b2, out);
}

// Round 3
// 182.570 us; speedup vs baseline: 1.3179x; 1.2935x over previous
//
#include <hip/hip_runtime.h>
#include <stdint.h>

typedef __attribute__((ext_vector_type(8))) _Float16 half8;  // MFMA f16 A/B frag (4 VGPRs)
typedef __attribute__((ext_vector_type(4))) float f32x4;     // MFMA C/D frag

// B=4, C=384, Q=384, H=256, K=256
// ws: [0, 393216) Wsplit fp16 [3][256][256] = W_h, W_u, W_hu, layout [k][h]
// NOTE: w1 is (K=256 rows, 3H=768 cols): W_m[k][h] = w1[k][m*256 + h]  (axis-0 is k!)

__device__ __forceinline__ float leaky(float x) { return fmaxf(x, 0.01f * x); }

template <int CTRL>
__device__ __forceinline__ float dpp_add(float x) {
  int t = __builtin_amdgcn_update_dpp(0, __float_as_int(x), CTRL, 0xF, 0xF, true);
  return x + __int_as_float(t);
}

// 16-lane sum (within each aligned 16-lane group): xor1, xor2, then +ror4 +ror8
__device__ __forceinline__ float row16_sum(float p) {
  p = dpp_add<0xB1>(p);   // quad_perm(1,0,3,2)  = xor 1
  p = dpp_add<0x4E>(p);   // quad_perm(2,3,0,1)  = xor 2
  p = dpp_add<0x124>(p);  // row_ror:4
  p = dpp_add<0x128>(p);  // row_ror:8  -> full 16-lane sum in every lane
  return p;
}

// ---------------- K0: split w1 (256 k-rows, 768 h-cols) -> fp16 [3][k][h] -----------
__global__ void k_convert(const float* __restrict__ w1, unsigned int* __restrict__ ws) {
  int d = blockIdx.x * 256 + threadIdx.x;        // 98304 dwords (2 fp16 each, along h)
  int m = d >> 15;                               // matrix 0..2
  int rem = d & 32767;
  int k = rem >> 7;
  int h2 = (rem & 127) * 2;
  float x0 = w1[k * 768 + m * 256 + h2];         // w1[k][m*256+h] — axis-0 is k
  float x1 = w1[k * 768 + m * 256 + h2 + 1];
  unsigned short p0 = __builtin_bit_cast(unsigned short, (_Float16)x0);
  unsigned short p1 = __builtin_bit_cast(unsigned short, (_Float16)x1);
  ws[d] = (unsigned int)p0 | ((unsigned int)p1 << 16);
}

// ---------------- K1: fused main kernel ---------------------------------------------
// Block: 16 q-rows x 256 k x 24 c. 256 threads = 4 waves, wave w owns k in [w*64, w*64+64),
// lane (quad,r) holds k = w*64 + 4r + j (j = 0..3)
// Structure (round-2): tuacc precomputed, A = u ⊙ h[c] per c, B = whu fixed in regs,
//   barrier-free c-loop, one final cross-wave combine.
// Round-3 fix: __launch_bounds__(256, 1). The (256,2) hint made the backend cap the
//   allocator at 128 VGPRs and spill ~100 regs into the c-loop (WRITE_SIZE 129 MB,
//   scratch thrashing L2->HBM). Live set is ~230: fits the architectural 256 cap with
//   no spills, and <=256 VGPRs still permits 2 waves/SIMD at runtime.
// Also: whu register-fill moved AFTER the term_h prologue to keep prologue peak RP low.
__global__ void __launch_bounds__(256, 1) k_main(
    const float* __restrict__ hp, const float* __restrict__ up,
    const _Float16* __restrict__ wsp,
    const float* __restrict__ b1, const float* __restrict__ w2,
    const float* __restrict__ b2, float* __restrict__ out) {
  __shared__ __align__(16) float thlds[24 * 256];      // term_h (pure), fp32, 24 KB
  __shared__ __align__(16) _Float16 hlds[24 * 256];    // h rows, fp16, 12 KB
  __shared__ float redw[24][4][16];                    // per-c per-wave partials, 6 KB

  const int tid = threadIdx.x;
  const int blk = blockIdx.x;            // 1536 = 4 b * 24 qt * 16 cc
  const int b = blk / 384;
  const int r0 = blk % 384;
  const int qt = r0 % 24;
  const int cc = r0 / 24;
  const int q0 = qt * 16;
  const int c0 = cc * 24;

  const int w = tid >> 6, l = tid & 63, quad = l >> 4, r = l & 15;
  const int kbase = w * 64 + r * 4;      // lane's 4 k-columns = kbase + j

  const _Float16* Wh = wsp;
  const _Float16* Wu = wsp + 65536;
  const _Float16* Whu = wsp + 131072;

  // ---- stage h rows into LDS as packed fp16, layout [c][h] linear ----
  for (int d = tid; d < 24 * 128; d += 256) {          // 3072 dwords
    int c = d >> 7;
    int hidx = (d & 127) * 2;
    const float* hr = hp + (b * 384 + c0 + c) * 256 + hidx;
    unsigned short p0 = __builtin_bit_cast(unsigned short, (_Float16)hr[0]);
    unsigned short p1 = __builtin_bit_cast(unsigned short, (_Float16)hr[1]);
    ((unsigned int*)hlds)[d] = (unsigned int)p0 | ((unsigned int)p1 << 16);
  }

  // ---- one-time register frags: u rows (A operand) ----
  half8 ufr[8];                          // u[q0+r][s*32+quad*8 .. +8]
  {
    const float* urow = up + (b * 384 + q0 + r) * 256 + quad * 8;
#pragma unroll
    for (int s = 0; s < 8; ++s) {
      float4 a0 = *(const float4*)(urow + s * 32);
      float4 a1 = *(const float4*)(urow + s * 32 + 4);
      half8 hv;
      hv[0] = (_Float16)a0.x; hv[1] = (_Float16)a0.y;
      hv[2] = (_Float16)a0.z; hv[3] = (_Float16)a0.w;
      hv[4] = (_Float16)a1.x; hv[5] = (_Float16)a1.y;
      hv[6] = (_Float16)a1.z; hv[7] = (_Float16)a1.w;
      ufr[s] = hv;
    }
  }

  // ---- tu pass: tuacc[j][ii] = b1[kbase+j] + term_u[q0+quad*4+ii][kbase+j] ----
  // (c-independent; Wu frags are transient)
  f32x4 tuacc[4];
  {
    f32x4 b1v = *(const f32x4*)(b1 + kbase);
#pragma unroll
    for (int j = 0; j < 4; ++j) tuacc[j] = (f32x4){b1v[j], b1v[j], b1v[j], b1v[j]};
#pragma unroll
    for (int s = 0; s < 8; ++s) {
#pragma unroll
      for (int j = 0; j < 4; ++j) {
        half8 wuf = *(const half8*)(Wu + (kbase + j) * 256 + s * 32 + quad * 8);
        tuacc[j] = __builtin_amdgcn_mfma_f32_16x16x32_f16(ufr[s], wuf, tuacc[j], 0, 0, 0);
      }
    }
  }

  __syncthreads();   // hlds ready

  // ---- prologue MFMA pass: term_h for the block's 24 c-rows -> thlds (pure, no b1) ----
#pragma unroll
  for (int ct = 0; ct < 2; ++ct) {
    f32x4 accq[4];
#pragma unroll
    for (int j = 0; j < 4; ++j) accq[j] = (f32x4){0.f, 0.f, 0.f, 0.f};
#pragma unroll
    for (int s = 0; s < 8; ++s) {
      half8 ha = (half8){};
      if (ct * 16 + r < 24) ha = *(const half8*)&hlds[(ct * 16 + r) * 256 + s * 32 + quad * 8];
#pragma unroll
      for (int j = 0; j < 4; ++j) {
        half8 wb = *(const half8*)(Wh + (kbase + j) * 256 + s * 32 + quad * 8);
        accq[j] = __builtin_amdgcn_mfma_f32_16x16x32_f16(ha, wb, accq[j], 0, 0, 0);
      }
    }
#pragma unroll
    for (int ii = 0; ii < 4; ++ii) {
      int crow = ct * 16 + quad * 4 + ii;
      if (crow < 24) {
        f32x4 v = {accq[0][ii], accq[1][ii], accq[2][ii], accq[3][ii]};
        *(f32x4*)&thlds[crow * 256 + kbase] = v;
      }
    }
  }

  // ---- persistent B operands: W_hu rows for this wave's 64 k (loaded late, after
  //      the prologue, so peak register pressure stays low until the c-loop) ----
  half8 whu[4][8];
#pragma unroll
  for (int j = 0; j < 4; ++j) {
    const _Float16* rowu = Whu + (kbase + j) * 256 + quad * 8;
#pragma unroll
    for (int s = 0; s < 8; ++s) whu[j][s] = *(const half8*)(rowu + s * 32);
  }

  __syncthreads();   // thlds ready

  // ---- main c-loop: barrier-free ----
  f32x4 w2v = *(const f32x4*)(w2 + kbase);
  f32x4 w2a = w2v * 0.505f;     // leaky(x)*w2 = w2*(0.505x + 0.495|x|)
  f32x4 w2b = w2v * 0.495f;

  for (int c = 0; c < 24; ++c) {
    f32x4 thv = *(const f32x4*)&thlds[c * 256 + kbase];
    f32x4 acc[4];
#pragma unroll
    for (int j = 0; j < 4; ++j) {
      float t = thv[j];
      acc[j] = tuacc[j] + (f32x4){t, t, t, t};
    }

#pragma unroll
    for (int s = 0; s < 8; ++s) {
      half8 hc = *(const half8*)&hlds[c * 256 + s * 32 + quad * 8];
      half8 au = ufr[s] * hc;                         // v_pk_mul_f16: A = u ⊙ h[c]
#pragma unroll
      for (int j = 0; j < 4; ++j)
        acc[j] = __builtin_amdgcn_mfma_f32_16x16x32_f16(au, whu[j][s], acc[j], 0, 0, 0);
    }

    // epilogue: layer-2 dot over this wave's 64 k, DPP-reduce over the 16 r-lanes
#pragma unroll
    for (int ii = 0; ii < 4; ++ii) {
      float p = 0.f;
#pragma unroll
      for (int j = 0; j < 4; ++j) {
        float sv = acc[j][ii];
        p = fmaf(w2a[j], sv, p);
        p = fmaf(w2b[j], fabsf(sv), p);
      }
      p = row16_sum(p);
      if (r == 0) redw[c][w][quad * 4 + ii] = p;
    }
  }

  __syncthreads();   // all partials in redw

  // ---- final cross-wave combine + bias + leaky + store ----
  const float b2v = b2[0];
  for (int idx = tid; idx < 24 * 16; idx += 256) {
    int c = idx >> 4;
    int q = idx & 15;
    float o = redw[c][0][q] + redw[c][1][q] + redw[c][2][q] + redw[c][3][q] + b2v;
    out[(b * 384 + c0 + c) * 384 + q0 + q] = leaky(o);
  }
}

extern "C" void kernel_launch(void* const* d_in, const int* in_sizes, int n_in,
                              void* d_out, int out_size, void* d_ws, size_t ws_size,
                              hipStream_t stream) {
  const float* hp = (const float*)d_in[0];   // (4,384,256)
  const float* up = (const float*)d_in[1];   // (4,384,256)
  const float* w1 = (const float*)d_in[2];   // (256,768) — axis-0 is k
  const float* b1 = (const float*)d_in[3];   // (256,)
  const float* w2 = (const float*)d_in[4];   // (1,256)
  const float* b2 = (const float*)d_in[5];   // (1,)
  float* out = (float*)d_out;                // (4,384,384)

  unsigned int* wsplit = (unsigned int*)d_ws;   // fp16 [3][256][256]

  k_convert<<<384, 256, 0, stream>>>(w1, wsplit);
  k_main<<<1536, 256, 0, stream>>>(hp, up, (const _Float16*)d_ws, b1, w2, b2, out);
}